// Round 1
// 1316.289 us; speedup vs baseline: 1.4595x; 1.4595x over previous
//
#include <hip/hip_runtime.h>
#include <hip/hip_bf16.h>
#include <cstdint>
#include <cstddef>

using u16 = unsigned short;

#define DEV static __device__ __forceinline__

DEV float bf2f(u16 u) {
  unsigned int x = ((unsigned int)u) << 16;
  float f;
  __builtin_memcpy(&f, &x, 4);
  return f;
}

DEV u16 f2bf(float f) {  // round-to-nearest-even bf16
  unsigned int x;
  __builtin_memcpy(&x, &f, 4);
  unsigned int r = (x + 0x7fffu + ((x >> 16) & 1u)) >> 16;
  return (u16)r;
}

typedef __bf16 bf16x8 __attribute__((ext_vector_type(8)));
typedef float f32x4 __attribute__((ext_vector_type(4)));

DEV f32x4 mfma_bf16(bf16x8 a, bf16x8 b, f32x4 c) {
  return __builtin_amdgcn_mfma_f32_16x16x32_bf16(a, b, c, 0, 0, 0);
}

// async global->LDS, 16B per lane; lds dest is wave-uniform base + lane*16
DEV void async_ld16(const void* g, void* lds) {
  __builtin_amdgcn_global_load_lds((const __attribute__((address_space(1))) void*)g,
                                   (__attribute__((address_space(3))) void*)lds,
                                   16, 0, 0);
}

// ---------------------------------------------------------------------------
// fp32 -> bf16 (RNE) weight conversion, grid-stride
// ---------------------------------------------------------------------------
__global__ __launch_bounds__(256) void k_cvt(const float* __restrict__ src,
                                             u16* __restrict__ dst, int n) {
  for (int i = blockIdx.x * 256 + threadIdx.x; i < n; i += gridDim.x * 256)
    dst[i] = f2bf(src[i]);
}

// ---------------------------------------------------------------------------
// GEMM: C[m,n] = sum_k A[m,k]*W[n,k] (+bias). A = Ahi (+Alo if SPLIT) bf16;
// W bf16 (pre-rounded). M%128==0, K%64==0, N arbitrary (clamped staging,
// bounds-checked store). 128x128 tile, 4 waves 2x2, 4x4 MFMA 16x16x32 each.
// ---------------------------------------------------------------------------
template <bool SPLIT, bool BIAS>
__global__ __launch_bounds__(256, 2) void gemm_bt(
    const u16* __restrict__ Ahi, const u16* __restrict__ Alo,
    const u16* __restrict__ Bw, float* __restrict__ Cf,
    const float* __restrict__ bias, int M, int N, int K, int ldc) {
  __shared__ __align__(16) u16 sA[128 * 64];
  __shared__ __align__(16) u16 sB[128 * 64];
  __shared__ __align__(16) u16 sAl[SPLIT ? 128 * 64 : 8];

  const int tid = threadIdx.x;
  const int wave = tid >> 6;
  const int lane = tid & 63;
  const int mBase = blockIdx.y * 128;
  const int nBase = blockIdx.x * 128;
  const int wm = wave >> 1;
  const int wn = wave & 1;

  f32x4 acc[4][4];
#pragma unroll
  for (int i = 0; i < 4; ++i)
#pragma unroll
    for (int j = 0; j < 4; ++j) acc[i][j] = f32x4{0.f, 0.f, 0.f, 0.f};

  const int rsub = lane >> 3;       // row within 8-row chunk
  const int ksub = (lane & 7) * 8;  // k element offset (8 bf16 = 16B)

  for (int k0 = 0; k0 < K; k0 += 64) {
#pragma unroll
    for (int it = 0; it < 4; ++it) {
      const int chunk = it * 4 + wave;  // wave-uniform
      const int row = chunk * 8 + rsub;
      async_ld16(Ahi + (size_t)(mBase + row) * K + (k0 + ksub), (char*)sA + chunk * 1024);
      if constexpr (SPLIT)
        async_ld16(Alo + (size_t)(mBase + row) * K + (k0 + ksub), (char*)sAl + chunk * 1024);
      int rn = nBase + row;
      if (rn > N - 1) rn = N - 1;  // clamp (junk cols never stored)
      async_ld16(Bw + (size_t)rn * K + (k0 + ksub), (char*)sB + chunk * 1024);
    }
    __syncthreads();

    const int rr = lane & 15;
    const int q8 = (lane >> 4) * 8;
#pragma unroll
    for (int ks = 0; ks < 64; ks += 32) {
      bf16x8 aH[4], bF[4], aL[4];
#pragma unroll
      for (int i = 0; i < 4; ++i) {
        aH[i] = *(const bf16x8*)(sA + (wm * 64 + i * 16 + rr) * 64 + ks + q8);
        bF[i] = *(const bf16x8*)(sB + (wn * 64 + i * 16 + rr) * 64 + ks + q8);
        if constexpr (SPLIT)
          aL[i] = *(const bf16x8*)(sAl + (wm * 64 + i * 16 + rr) * 64 + ks + q8);
      }
#pragma unroll
      for (int i = 0; i < 4; ++i)
#pragma unroll
        for (int j = 0; j < 4; ++j) {
          acc[i][j] = mfma_bf16(aH[i], bF[j], acc[i][j]);
          if constexpr (SPLIT) acc[i][j] = mfma_bf16(aL[i], bF[j], acc[i][j]);
        }
    }
    __syncthreads();
  }

  // C/D layout (m89/m91): col = lane&15, row = (lane>>4)*4 + reg
  const int r0 = (lane >> 4) * 4;
  const int cn = lane & 15;
#pragma unroll
  for (int i = 0; i < 4; ++i) {
    const int mm = mBase + wm * 64 + i * 16 + r0;
#pragma unroll
    for (int j = 0; j < 4; ++j) {
      const int nn = nBase + wn * 64 + j * 16 + cn;
      if (nn < N) {
        float bv = 0.f;
        if constexpr (BIAS) bv = bias[nn];
#pragma unroll
        for (int r = 0; r < 4; ++r)
          Cf[(size_t)(mm + r) * ldc + nn] = acc[i][j][r] + bv;
      }
    }
  }
}

// ---------------------------------------------------------------------------
// Embedding gather (fp32 in) -> bf16 hi/lo
// ---------------------------------------------------------------------------
__global__ __launch_bounds__(256) void k_embed(const int* __restrict__ tok,
                                               const float* __restrict__ emb,
                                               u16* __restrict__ xh,
                                               u16* __restrict__ xl) {
  const int m = blockIdx.x;
  const float* src = emb + (size_t)tok[m] * 768;
  for (int d = threadIdx.x; d < 768; d += 256) {
    const float v = src[d];
    const u16 h = f2bf(v);
    xh[(size_t)m * 768 + d] = h;
    xl[(size_t)m * 768 + d] = f2bf(v - bf2f(h));
  }
}

// ---------------------------------------------------------------------------
// Depthwise causal conv (K=4) + bias + silu -> fp32 + bf16 hi/lo
// xz: (2048,3072) fp32, xin = cols [0,1536)
// ---------------------------------------------------------------------------
__global__ __launch_bounds__(256) void k_conv(const float* __restrict__ xz,
                                              const float* __restrict__ cw,
                                              const float* __restrict__ cb,
                                              float* __restrict__ xinc,
                                              u16* __restrict__ xih,
                                              u16* __restrict__ xil) {
  const int idx = blockIdx.x * 256 + threadIdx.x;  // 2048*1536
  const int e = idx % 1536;
  const int m = idx / 1536;
  const int t = m & 1023;
  const int b = m >> 10;
  float acc = cb[e];
#pragma unroll
  for (int k = 0; k < 4; ++k) {
    const int tt = t - 3 + k;
    if (tt >= 0) acc += xz[(size_t)((b << 10) + tt) * 3072 + e] * cw[e * 4 + k];
  }
  const float s = acc / (1.f + __expf(-acc));  // silu
  xinc[idx] = s;
  const u16 h = f2bf(s);
  xih[idx] = h;
  xil[idx] = f2bf(s - bf2f(h));
}

// ---------------------------------------------------------------------------
// dt_proj (K=48) + bias + softplus -> delta fp32. One block per row m.
// ---------------------------------------------------------------------------
__global__ __launch_bounds__(256) void k_dt(const float* __restrict__ dbc,
                                            const float* __restrict__ dtw,
                                            const float* __restrict__ dtb,
                                            float* __restrict__ delta) {
  const int m = blockIdx.x;
  __shared__ float sd[48];
  if (threadIdx.x < 48) sd[threadIdx.x] = dbc[m * 80 + threadIdx.x];
  __syncthreads();
  for (int e = threadIdx.x; e < 1536; e += 256) {
    float acc = dtb[e];
#pragma unroll
    for (int r = 0; r < 48; ++r) acc += sd[r] * dtw[e * 48 + r];
    const float sp = (acc > 20.f) ? acc : log1pf(__expf(acc));
    delta[m * 1536 + e] = sp;
  }
}

// ---------------------------------------------------------------------------
// Chunk-parallel selective scan.  h_t = dA_t*h_{t-1} + dBx_t is linear, so:
//  pass1: per 64-step chunk compute P = prod(dA), Q = local h (from 0)
//  fix:   tiny sequential combine over the 16 chunks -> h_start per chunk
//  pass2: replay each chunk from its h_start (bit-identical inner ops to the
//         old sequential scan) and emit gated y.
// Parallelism: 192 -> 3072 blocks (latency-bound -> VALU-throughput-bound).
// ---------------------------------------------------------------------------
#define SCAN_NC 16
#define SCAN_CL 64  // 1024 / SCAN_NC

__global__ __launch_bounds__(256) void k_scan1(
    const float* __restrict__ delta, const float* __restrict__ xinc,
    const float* __restrict__ dbc, const float* __restrict__ alog,
    float* __restrict__ chP, float* __restrict__ chQ) {
  const int b = blockIdx.y;
  const int c = blockIdx.z;
  const int e = blockIdx.x * 16 + (threadIdx.x >> 4);
  const int n = threadIdx.x & 15;
  const float Aen = -__expf(alog[e * 16 + n]);
  const int m0 = (b << 10) + c * SCAN_CL;
  float h = 0.f, P = 1.f;
  float dl = delta[m0 * 1536 + e];
  float xi = xinc[m0 * 1536 + e];
  float Bn = dbc[m0 * 80 + 48 + n];
  for (int t = 0; t < SCAN_CL; ++t) {
    const float dl_c = dl, xi_c = xi, Bn_c = Bn;
    if (t < SCAN_CL - 1) {
      const int m2 = m0 + t + 1;
      dl = delta[m2 * 1536 + e];
      xi = xinc[m2 * 1536 + e];
      Bn = dbc[m2 * 80 + 48 + n];
    }
    const float dA = __expf(dl_c * Aen);
    P *= dA;
    h = dA * h + (dl_c * xi_c) * Bn_c;
  }
  const size_t idx = (((size_t)b * SCAN_NC + c) * 1536 + e) * 16 + n;
  chP[idx] = P;
  chQ[idx] = h;
}

__global__ __launch_bounds__(256) void k_scan_fix(const float* __restrict__ chP,
                                                  const float* __restrict__ chQ,
                                                  float* __restrict__ hst) {
  const int b = blockIdx.y;
  const int e = blockIdx.x * 16 + (threadIdx.x >> 4);
  const int n = threadIdx.x & 15;
  float h = 0.f;
#pragma unroll
  for (int c = 0; c < SCAN_NC; ++c) {
    const size_t idx = (((size_t)b * SCAN_NC + c) * 1536 + e) * 16 + n;
    hst[idx] = h;
    h = chP[idx] * h + chQ[idx];
  }
}

__global__ __launch_bounds__(256) void k_scan2(
    const float* __restrict__ delta, const float* __restrict__ xinc,
    const float* __restrict__ dbc, const float* __restrict__ xz,
    const float* __restrict__ alog, const float* __restrict__ dpar,
    const float* __restrict__ hst, u16* __restrict__ ymh,
    u16* __restrict__ yml) {
  const int b = blockIdx.y;
  const int c = blockIdx.z;
  const int e = blockIdx.x * 16 + (threadIdx.x >> 4);
  const int n = threadIdx.x & 15;
  const float Aen = -__expf(alog[e * 16 + n]);
  const float dp = dpar[e];
  const int m0 = (b << 10) + c * SCAN_CL;
  float h = hst[(((size_t)b * SCAN_NC + c) * 1536 + e) * 16 + n];
  float dl = delta[m0 * 1536 + e];
  float xi = xinc[m0 * 1536 + e];
  float Bn = dbc[m0 * 80 + 48 + n];
  float Cn = dbc[m0 * 80 + 64 + n];
  float zz = xz[(size_t)m0 * 3072 + 1536 + e];
  for (int t = 0; t < SCAN_CL; ++t) {
    const float dl_c = dl, xi_c = xi, Bn_c = Bn, Cn_c = Cn, zz_c = zz;
    if (t < SCAN_CL - 1) {  // prefetch next step
      const int m2 = m0 + t + 1;
      dl = delta[m2 * 1536 + e];
      xi = xinc[m2 * 1536 + e];
      Bn = dbc[m2 * 80 + 48 + n];
      Cn = dbc[m2 * 80 + 64 + n];
      zz = xz[(size_t)m2 * 3072 + 1536 + e];
    }
    const float dA = __expf(dl_c * Aen);
    h = dA * h + (dl_c * xi_c) * Bn_c;
    float p = h * Cn_c;
    p += __shfl_xor(p, 1);
    p += __shfl_xor(p, 2);
    p += __shfl_xor(p, 4);
    p += __shfl_xor(p, 8);
    if (n == 0) {
      const float y = p + dp * xi_c;
      const float sz = zz_c / (1.f + __expf(-zz_c));
      const float ym = y * sz;
      const int mt = m0 + t;
      const u16 hh = f2bf(ym);
      ymh[mt * 1536 + e] = hh;
      yml[mt * 1536 + e] = f2bf(ym - bf2f(hh));
    }
  }
}

// ---------------------------------------------------------------------------
// LayerNorm over 768 + affine -> bf16 hi/lo. One block per row.
// ---------------------------------------------------------------------------
__global__ __launch_bounds__(256) void k_ln(const float* __restrict__ g,
                                            const float* __restrict__ w,
                                            const float* __restrict__ bb,
                                            u16* __restrict__ xh,
                                            u16* __restrict__ xl) {
  const int m = blockIdx.x;
  const float* row = g + (size_t)m * 768;
  const int tid = threadIdx.x;
  const float v0 = row[tid], v1 = row[tid + 256], v2 = row[tid + 512];
  float s = v0 + v1 + v2;
#pragma unroll
  for (int o = 32; o > 0; o >>= 1) s += __shfl_xor(s, o);
  __shared__ float red[4];
  if ((tid & 63) == 0) red[tid >> 6] = s;
  __syncthreads();
  const float mu = (red[0] + red[1] + red[2] + red[3]) * (1.f / 768.f);
  const float d0 = v0 - mu, d1 = v1 - mu, d2 = v2 - mu;
  float q = d0 * d0 + d1 * d1 + d2 * d2;
#pragma unroll
  for (int o = 32; o > 0; o >>= 1) q += __shfl_xor(q, o);
  __syncthreads();
  if ((tid & 63) == 0) red[tid >> 6] = q;
  __syncthreads();
  const float var = (red[0] + red[1] + red[2] + red[3]) * (1.f / 768.f);
  const float rs = rsqrtf(var + 1e-5f);
  const float dd[3] = {d0, d1, d2};
#pragma unroll
  for (int i = 0; i < 3; ++i) {
    const int d = tid + i * 256;
    const float y = dd[i] * rs * w[d] + bb[d];
    const u16 h = f2bf(y);
    xh[(size_t)m * 768 + d] = h;
    xl[(size_t)m * 768 + d] = f2bf(y - bf2f(h));
  }
}

// ---------------------------------------------------------------------------
extern "C" void kernel_launch(void* const* d_in, const int* in_sizes, int n_in,
                              void* d_out, int out_size, void* d_ws, size_t ws_size,
                              hipStream_t stream) {
  const int* tokens = (const int*)d_in[0];
  const float* embed = (const float*)d_in[1];
  const float* in_w = (const float*)d_in[2];
  const float* conv_w = (const float*)d_in[3];
  const float* conv_b = (const float*)d_in[4];
  const float* xp_w = (const float*)d_in[5];
  const float* dt_w = (const float*)d_in[6];
  const float* dt_b = (const float*)d_in[7];
  const float* A_log = (const float*)d_in[8];
  const float* D_par = (const float*)d_in[9];
  const float* out_w = (const float*)d_in[10];
  const float* ln_w = (const float*)d_in[11];
  const float* ln_b = (const float*)d_in[12];
  const float* head_w = (const float*)d_in[13];
  const float* head_b = (const float*)d_in[14];

  char* p = (char*)d_ws;
  auto alloc = [&](size_t bytes) {
    char* r = p;
    p += (bytes + 255) & ~(size_t)255;
    return r;
  };
  float* xz = (float*)alloc(2048ull * 3072 * 4);     // in_proj out (xin | z)
  float* xinc = (float*)alloc(2048ull * 1536 * 4);   // conv+silu fp32
  u16* xih = (u16*)alloc(2048ull * 1536 * 2);        // conv+silu hi
  u16* xil = (u16*)alloc(2048ull * 1536 * 2);        // conv+silu lo
  float* dbc = (float*)alloc(2048ull * 80 * 4);      // x_proj out
  float* delta = (float*)alloc(2048ull * 1536 * 4);  // softplus(dt_proj)
  u16* ymh = (u16*)alloc(2048ull * 1536 * 2);        // gated scan out hi
  u16* yml = (u16*)alloc(2048ull * 1536 * 2);        // gated scan out lo
  float* gout = (float*)alloc(2048ull * 768 * 4);    // out_proj (pre-LN)
  u16* xh = (u16*)alloc(2048ull * 768 * 2);          // layer input hi
  u16* xl = (u16*)alloc(2048ull * 768 * 2);          // layer input lo
  u16* w_in_h = (u16*)alloc(2ull * 3072 * 768 * 2);  // bf16 weights
  u16* w_xp_h = (u16*)alloc(2ull * 80 * 1536 * 2);
  u16* w_out_h = (u16*)alloc(2ull * 768 * 1536 * 2);
  u16* w_head_h = (u16*)alloc(32000ull * 768 * 2);
  float* chP = (float*)alloc(2ull * SCAN_NC * 1536 * 16 * 4);  // chunk prod(dA)
  float* chQ = (float*)alloc(2ull * SCAN_NC * 1536 * 16 * 4);  // chunk local h
  float* hst = (float*)alloc(2ull * SCAN_NC * 1536 * 16 * 4);  // chunk h_start

  // weight bf16 pre-pass
  k_cvt<<<2048, 256, 0, stream>>>(in_w, w_in_h, 2 * 3072 * 768);
  k_cvt<<<256, 256, 0, stream>>>(xp_w, w_xp_h, 2 * 80 * 1536);
  k_cvt<<<1024, 256, 0, stream>>>(out_w, w_out_h, 2 * 768 * 1536);
  k_cvt<<<4096, 256, 0, stream>>>(head_w, w_head_h, 32000 * 768);

  k_embed<<<2048, 256, 0, stream>>>(tokens, embed, xh, xl);

  for (int l = 0; l < 2; ++l) {
    gemm_bt<true, false><<<dim3(24, 16), 256, 0, stream>>>(
        xh, xl, w_in_h + (size_t)l * 2359296, xz, nullptr, 2048, 3072, 768, 3072);

    k_conv<<<12288, 256, 0, stream>>>(xz, conv_w + l * 6144, conv_b + l * 1536, xinc, xih, xil);

    gemm_bt<true, false><<<dim3(1, 16), 256, 0, stream>>>(
        xih, xil, w_xp_h + (size_t)l * 122880, dbc, nullptr, 2048, 80, 1536, 80);

    k_dt<<<2048, 256, 0, stream>>>(dbc, dt_w + (size_t)l * 73728, dt_b + l * 1536, delta);

    k_scan1<<<dim3(96, 2, SCAN_NC), 256, 0, stream>>>(
        delta, xinc, dbc, A_log + l * 24576, chP, chQ);
    k_scan_fix<<<dim3(96, 2), 256, 0, stream>>>(chP, chQ, hst);
    k_scan2<<<dim3(96, 2, SCAN_NC), 256, 0, stream>>>(
        delta, xinc, dbc, xz, A_log + l * 24576, D_par + l * 1536, hst, ymh, yml);

    gemm_bt<true, false><<<dim3(6, 16), 256, 0, stream>>>(
        ymh, yml, w_out_h + (size_t)l * 1179648, gout, nullptr, 2048, 768, 1536, 768);

    k_ln<<<2048, 256, 0, stream>>>(gout, ln_w + l * 768, ln_b + l * 768, xh, xl);
  }

  gemm_bt<true, true><<<dim3(250, 16), 256, 0, stream>>>(
      xh, xl, w_head_h, (float*)d_out, head_b, 2048, 32000, 768, 32000);
}

// Round 2
// 1288.763 us; speedup vs baseline: 1.4907x; 1.0214x over previous
//
#include <hip/hip_runtime.h>
#include <hip/hip_bf16.h>
#include <cstdint>
#include <cstddef>

using u16 = unsigned short;

#define DEV static __device__ __forceinline__

DEV float bf2f(u16 u) {
  unsigned int x = ((unsigned int)u) << 16;
  float f;
  __builtin_memcpy(&f, &x, 4);
  return f;
}

DEV u16 f2bf(float f) {  // round-to-nearest-even bf16
  unsigned int x;
  __builtin_memcpy(&x, &f, 4);
  unsigned int r = (x + 0x7fffu + ((x >> 16) & 1u)) >> 16;
  return (u16)r;
}

typedef __bf16 bf16x8 __attribute__((ext_vector_type(8)));
typedef float f32x4 __attribute__((ext_vector_type(4)));

DEV f32x4 mfma_bf16(bf16x8 a, bf16x8 b, f32x4 c) {
  return __builtin_amdgcn_mfma_f32_16x16x32_bf16(a, b, c, 0, 0, 0);
}

// async global->LDS, 16B per lane; lds dest is wave-uniform base + lane*16
DEV void async_ld16(const void* g, void* lds) {
  __builtin_amdgcn_global_load_lds((const __attribute__((address_space(1))) void*)g,
                                   (__attribute__((address_space(3))) void*)lds,
                                   16, 0, 0);
}

// ---------------------------------------------------------------------------
// fp32 -> bf16 (RNE) weight conversion, grid-stride
// ---------------------------------------------------------------------------
__global__ __launch_bounds__(256) void k_cvt(const float* __restrict__ src,
                                             u16* __restrict__ dst, int n) {
  for (int i = blockIdx.x * 256 + threadIdx.x; i < n; i += gridDim.x * 256)
    dst[i] = f2bf(src[i]);
}

__global__ __launch_bounds__(256) void k_zero(float* __restrict__ p, int n) {
  const int i = blockIdx.x * 256 + threadIdx.x;
  if (i < n) p[i] = 0.f;
}

// ---------------------------------------------------------------------------
// gemm2: C[m,n] = sum_k A[m,k]*W[n,k] (+bias). 128x256 tile, 512 thr (8 waves
// 2Mx4N), double-buffered LDS (128 KB), stage-before-compute overlap, XOR LDS
// swizzle (pre-swizzled global source + swizzled ds_read), setprio, XCD-swz.
// Requires: M%128==0, N%256==0, K%64==0, gridDim.x%8==0.
// Block-order: mb fastest (16 m-blocks share one B panel -> same XCD L2).
// ---------------------------------------------------------------------------
template <bool SPLIT, bool BIAS>
__global__ __launch_bounds__(512, 2) void gemm2(
    const u16* __restrict__ Ahi, const u16* __restrict__ Alo,
    const u16* __restrict__ Bw, float* __restrict__ Cf,
    const float* __restrict__ bias, int M, int N, int K, int ldc) {
  __shared__ __align__(16) u16 sA[2][128 * 64];
  __shared__ __align__(16) u16 sAl[SPLIT ? 2 : 1][128 * 64];
  __shared__ __align__(16) u16 sB[2][256 * 64];

  const int tid = threadIdx.x;
  const int wave = tid >> 6;
  const int lane = tid & 63;
  const int nwg = gridDim.x;
  // bijective XCD swizzle (nwg % 8 == 0 for all our launches)
  const int w = (blockIdx.x & 7) * (nwg >> 3) + (blockIdx.x >> 3);
  const int mBlocks = M >> 7;
  const int mb = w % mBlocks;
  const int nb = w / mBlocks;
  const int mBase = mb * 128;
  const int nBase = nb * 256;
  const int wm = wave >> 2;  // 0..1
  const int wn = wave & 3;   // 0..3

  f32x4 acc[4][4];
#pragma unroll
  for (int i = 0; i < 4; ++i)
#pragma unroll
    for (int j = 0; j < 4; ++j) acc[i][j] = f32x4{0.f, 0.f, 0.f, 0.f};

  // staging: per round, 512 thr move 8 KB (64 rows x 64k u16). lane l: row
  // base+(l>>3), k-slot (l&7)^((l>>3)&7)  [inverse-XOR source so that LDS
  // linear dest + XOR read = conflict-free layout; rule #21 both-sides]
  const int rl = lane >> 3;        // row within wave's 8-row strip
  const int sw = (lane & 7) ^ rl;  // pre-swizzled k-slot (involution)

  auto stage = [&](int bf, int k0) {
    const int koff = k0 + sw * 8;
#pragma unroll
    for (int r = 0; r < 2; ++r) {
      const int row = r * 64 + wave * 8;  // wave-uniform
      async_ld16(Ahi + (size_t)(mBase + row + rl) * K + koff,
                 (u16*)sA[bf] + row * 64);
    }
    if constexpr (SPLIT) {
#pragma unroll
      for (int r = 0; r < 2; ++r) {
        const int row = r * 64 + wave * 8;
        async_ld16(Alo + (size_t)(mBase + row + rl) * K + koff,
                   (u16*)sAl[bf] + row * 64);
      }
    }
#pragma unroll
    for (int r = 0; r < 4; ++r) {
      const int row = r * 64 + wave * 8;
      async_ld16(Bw + (size_t)(nBase + row + rl) * K + koff,
                 (u16*)sB[bf] + row * 64);
    }
  };

  const int rr = lane & 15;
  const int qh = lane >> 4;  // 0..3 (16B quarter within 64-elem row half)

  stage(0, 0);
  __syncthreads();  // compiler drains vmcnt(0) before s_barrier

  const int nt = K >> 6;
  int cur = 0;
  for (int t = 0; t < nt; ++t) {
    if (t + 1 < nt) stage(cur ^ 1, (t + 1) * 64);  // issue-early: overlaps MFMA
#pragma unroll
    for (int ph = 0; ph < 4; ++ph) {
      const int ks = (ph >> 1) * 32;
      const int ih = (ph & 1) * 2;
      const int q = (ks >> 3) + qh;
      bf16x8 aH[2], aL[2], bF[4];
#pragma unroll
      for (int i = 0; i < 2; ++i) {
        const int ra = wm * 64 + (ih + i) * 16 + rr;
        const int off = ra * 64 + ((q ^ (ra & 7)) << 3);
        aH[i] = *(const bf16x8*)((const u16*)sA[cur] + off);
        if constexpr (SPLIT) aL[i] = *(const bf16x8*)((const u16*)sAl[cur] + off);
      }
#pragma unroll
      for (int j = 0; j < 4; ++j) {
        const int rb = wn * 64 + j * 16 + rr;
        bF[j] = *(const bf16x8*)((const u16*)sB[cur] + rb * 64 + ((q ^ (rb & 7)) << 3));
      }
      __builtin_amdgcn_s_setprio(1);
#pragma unroll
      for (int i = 0; i < 2; ++i)
#pragma unroll
        for (int j = 0; j < 4; ++j) {
          acc[ih + i][j] = mfma_bf16(aH[i], bF[j], acc[ih + i][j]);
          if constexpr (SPLIT) acc[ih + i][j] = mfma_bf16(aL[i], bF[j], acc[ih + i][j]);
        }
      __builtin_amdgcn_s_setprio(0);
    }
    __syncthreads();  // drains stage vmcnt (loads ~1 tile old) + WAR for swap
    cur ^= 1;
  }

  // C/D layout: col = lane&15, row = (lane>>4)*4 + reg
  const int r0 = (lane >> 4) * 4;
  const int cn = lane & 15;
#pragma unroll
  for (int i = 0; i < 4; ++i) {
    const int mm = mBase + wm * 64 + i * 16 + r0;
#pragma unroll
    for (int j = 0; j < 4; ++j) {
      const int nn = nBase + wn * 64 + j * 16 + cn;
      float bv = 0.f;
      if constexpr (BIAS) bv = bias[nn];
#pragma unroll
      for (int r = 0; r < 4; ++r)
        Cf[(size_t)(mm + r) * ldc + nn] = acc[i][j][r] + bv;
    }
  }
}

// ---------------------------------------------------------------------------
// GEMM (legacy 128x128): used for skinny/odd-N shapes, now with split-K
// (ATOMIC=true: accumulate into pre-zeroed C via atomicAdd over K-chunks).
// ---------------------------------------------------------------------------
template <bool SPLIT, bool BIAS, bool ATOMIC>
__global__ __launch_bounds__(256, 2) void gemm_bt(
    const u16* __restrict__ Ahi, const u16* __restrict__ Alo,
    const u16* __restrict__ Bw, float* __restrict__ Cf,
    const float* __restrict__ bias, int M, int N, int K, int ldc, int kChunk) {
  __shared__ __align__(16) u16 sA[128 * 64];
  __shared__ __align__(16) u16 sB[128 * 64];
  __shared__ __align__(16) u16 sAl[SPLIT ? 128 * 64 : 8];

  const int tid = threadIdx.x;
  const int wave = tid >> 6;
  const int lane = tid & 63;
  const int mBase = blockIdx.y * 128;
  const int nBase = blockIdx.x * 128;
  const int kBeg = blockIdx.z * kChunk;
  const int wm = wave >> 1;
  const int wn = wave & 1;

  f32x4 acc[4][4];
#pragma unroll
  for (int i = 0; i < 4; ++i)
#pragma unroll
    for (int j = 0; j < 4; ++j) acc[i][j] = f32x4{0.f, 0.f, 0.f, 0.f};

  const int rsub = lane >> 3;       // row within 8-row chunk
  const int ksub = (lane & 7) * 8;  // k element offset (8 bf16 = 16B)

  for (int k0 = kBeg; k0 < kBeg + kChunk; k0 += 64) {
#pragma unroll
    for (int it = 0; it < 4; ++it) {
      const int chunk = it * 4 + wave;  // wave-uniform
      const int row = chunk * 8 + rsub;
      async_ld16(Ahi + (size_t)(mBase + row) * K + (k0 + ksub), (char*)sA + chunk * 1024);
      if constexpr (SPLIT)
        async_ld16(Alo + (size_t)(mBase + row) * K + (k0 + ksub), (char*)sAl + chunk * 1024);
      int rn = nBase + row;
      if (rn > N - 1) rn = N - 1;  // clamp (junk cols never stored)
      async_ld16(Bw + (size_t)rn * K + (k0 + ksub), (char*)sB + chunk * 1024);
    }
    __syncthreads();

    const int rr = lane & 15;
    const int q8 = (lane >> 4) * 8;
#pragma unroll
    for (int ks = 0; ks < 64; ks += 32) {
      bf16x8 aH[4], bF[4], aL[4];
#pragma unroll
      for (int i = 0; i < 4; ++i) {
        aH[i] = *(const bf16x8*)(sA + (wm * 64 + i * 16 + rr) * 64 + ks + q8);
        bF[i] = *(const bf16x8*)(sB + (wn * 64 + i * 16 + rr) * 64 + ks + q8);
        if constexpr (SPLIT)
          aL[i] = *(const bf16x8*)(sAl + (wm * 64 + i * 16 + rr) * 64 + ks + q8);
      }
#pragma unroll
      for (int i = 0; i < 4; ++i)
#pragma unroll
        for (int j = 0; j < 4; ++j) {
          acc[i][j] = mfma_bf16(aH[i], bF[j], acc[i][j]);
          if constexpr (SPLIT) acc[i][j] = mfma_bf16(aL[i], bF[j], acc[i][j]);
        }
    }
    __syncthreads();
  }

  // C/D layout: col = lane&15, row = (lane>>4)*4 + reg
  const int r0 = (lane >> 4) * 4;
  const int cn = lane & 15;
#pragma unroll
  for (int i = 0; i < 4; ++i) {
    const int mm = mBase + wm * 64 + i * 16 + r0;
#pragma unroll
    for (int j = 0; j < 4; ++j) {
      const int nn = nBase + wn * 64 + j * 16 + cn;
      if (nn < N) {
        float bv = 0.f;
        if constexpr (BIAS) bv = bias[nn];
#pragma unroll
        for (int r = 0; r < 4; ++r) {
          if constexpr (ATOMIC)
            atomicAdd(&Cf[(size_t)(mm + r) * ldc + nn], acc[i][j][r]);
          else
            Cf[(size_t)(mm + r) * ldc + nn] = acc[i][j][r] + bv;
        }
      }
    }
  }
}

// ---------------------------------------------------------------------------
// Embedding gather (fp32 in) -> bf16 hi/lo
// ---------------------------------------------------------------------------
__global__ __launch_bounds__(256) void k_embed(const int* __restrict__ tok,
                                               const float* __restrict__ emb,
                                               u16* __restrict__ xh,
                                               u16* __restrict__ xl) {
  const int m = blockIdx.x;
  const float* src = emb + (size_t)tok[m] * 768;
  for (int d = threadIdx.x; d < 768; d += 256) {
    const float v = src[d];
    const u16 h = f2bf(v);
    xh[(size_t)m * 768 + d] = h;
    xl[(size_t)m * 768 + d] = f2bf(v - bf2f(h));
  }
}

// ---------------------------------------------------------------------------
// Depthwise causal conv (K=4) + bias + silu -> fp32 + bf16 hi/lo
// xz: (2048,3072) fp32, xin = cols [0,1536)
// ---------------------------------------------------------------------------
__global__ __launch_bounds__(256) void k_conv(const float* __restrict__ xz,
                                              const float* __restrict__ cw,
                                              const float* __restrict__ cb,
                                              float* __restrict__ xinc,
                                              u16* __restrict__ xih,
                                              u16* __restrict__ xil) {
  const int idx = blockIdx.x * 256 + threadIdx.x;  // 2048*1536
  const int e = idx % 1536;
  const int m = idx / 1536;
  const int t = m & 1023;
  const int b = m >> 10;
  float acc = cb[e];
#pragma unroll
  for (int k = 0; k < 4; ++k) {
    const int tt = t - 3 + k;
    if (tt >= 0) acc += xz[(size_t)((b << 10) + tt) * 3072 + e] * cw[e * 4 + k];
  }
  const float s = acc / (1.f + __expf(-acc));  // silu
  xinc[idx] = s;
  const u16 h = f2bf(s);
  xih[idx] = h;
  xil[idx] = f2bf(s - bf2f(h));
}

// ---------------------------------------------------------------------------
// dt_proj (K=48) + bias + softplus -> delta fp32. One block per row m.
// ---------------------------------------------------------------------------
__global__ __launch_bounds__(256) void k_dt(const float* __restrict__ dbc,
                                            const float* __restrict__ dtw,
                                            const float* __restrict__ dtb,
                                            float* __restrict__ delta) {
  const int m = blockIdx.x;
  __shared__ float sd[48];
  if (threadIdx.x < 48) sd[threadIdx.x] = dbc[m * 80 + threadIdx.x];
  __syncthreads();
  for (int e = threadIdx.x; e < 1536; e += 256) {
    float acc = dtb[e];
#pragma unroll
    for (int r = 0; r < 48; ++r) acc += sd[r] * dtw[e * 48 + r];
    const float sp = (acc > 20.f) ? acc : log1pf(__expf(acc));
    delta[m * 1536 + e] = sp;
  }
}

// ---------------------------------------------------------------------------
// Chunk-parallel selective scan (pass1 / combine / pass2).
// ---------------------------------------------------------------------------
#define SCAN_NC 16
#define SCAN_CL 64  // 1024 / SCAN_NC

__global__ __launch_bounds__(256) void k_scan1(
    const float* __restrict__ delta, const float* __restrict__ xinc,
    const float* __restrict__ dbc, const float* __restrict__ alog,
    float* __restrict__ chP, float* __restrict__ chQ) {
  const int b = blockIdx.y;
  const int c = blockIdx.z;
  const int e = blockIdx.x * 16 + (threadIdx.x >> 4);
  const int n = threadIdx.x & 15;
  const float Aen = -__expf(alog[e * 16 + n]);
  const int m0 = (b << 10) + c * SCAN_CL;
  float h = 0.f, P = 1.f;
  float dl = delta[m0 * 1536 + e];
  float xi = xinc[m0 * 1536 + e];
  float Bn = dbc[m0 * 80 + 48 + n];
  for (int t = 0; t < SCAN_CL; ++t) {
    const float dl_c = dl, xi_c = xi, Bn_c = Bn;
    if (t < SCAN_CL - 1) {
      const int m2 = m0 + t + 1;
      dl = delta[m2 * 1536 + e];
      xi = xinc[m2 * 1536 + e];
      Bn = dbc[m2 * 80 + 48 + n];
    }
    const float dA = __expf(dl_c * Aen);
    P *= dA;
    h = dA * h + (dl_c * xi_c) * Bn_c;
  }
  const size_t idx = (((size_t)b * SCAN_NC + c) * 1536 + e) * 16 + n;
  chP[idx] = P;
  chQ[idx] = h;
}

__global__ __launch_bounds__(256) void k_scan_fix(const float* __restrict__ chP,
                                                  const float* __restrict__ chQ,
                                                  float* __restrict__ hst) {
  const int b = blockIdx.y;
  const int e = blockIdx.x * 16 + (threadIdx.x >> 4);
  const int n = threadIdx.x & 15;
  float h = 0.f;
#pragma unroll
  for (int c = 0; c < SCAN_NC; ++c) {
    const size_t idx = (((size_t)b * SCAN_NC + c) * 1536 + e) * 16 + n;
    hst[idx] = h;
    h = chP[idx] * h + chQ[idx];
  }
}

__global__ __launch_bounds__(256) void k_scan2(
    const float* __restrict__ delta, const float* __restrict__ xinc,
    const float* __restrict__ dbc, const float* __restrict__ xz,
    const float* __restrict__ alog, const float* __restrict__ dpar,
    const float* __restrict__ hst, u16* __restrict__ ymh,
    u16* __restrict__ yml) {
  const int b = blockIdx.y;
  const int c = blockIdx.z;
  const int e = blockIdx.x * 16 + (threadIdx.x >> 4);
  const int n = threadIdx.x & 15;
  const float Aen = -__expf(alog[e * 16 + n]);
  const float dp = dpar[e];
  const int m0 = (b << 10) + c * SCAN_CL;
  float h = hst[(((size_t)b * SCAN_NC + c) * 1536 + e) * 16 + n];
  float dl = delta[m0 * 1536 + e];
  float xi = xinc[m0 * 1536 + e];
  float Bn = dbc[m0 * 80 + 48 + n];
  float Cn = dbc[m0 * 80 + 64 + n];
  float zz = xz[(size_t)m0 * 3072 + 1536 + e];
  for (int t = 0; t < SCAN_CL; ++t) {
    const float dl_c = dl, xi_c = xi, Bn_c = Bn, Cn_c = Cn, zz_c = zz;
    if (t < SCAN_CL - 1) {  // prefetch next step
      const int m2 = m0 + t + 1;
      dl = delta[m2 * 1536 + e];
      xi = xinc[m2 * 1536 + e];
      Bn = dbc[m2 * 80 + 48 + n];
      Cn = dbc[m2 * 80 + 64 + n];
      zz = xz[(size_t)m2 * 3072 + 1536 + e];
    }
    const float dA = __expf(dl_c * Aen);
    h = dA * h + (dl_c * xi_c) * Bn_c;
    float p = h * Cn_c;
    p += __shfl_xor(p, 1);
    p += __shfl_xor(p, 2);
    p += __shfl_xor(p, 4);
    p += __shfl_xor(p, 8);
    if (n == 0) {
      const float y = p + dp * xi_c;
      const float sz = zz_c / (1.f + __expf(-zz_c));
      const float ym = y * sz;
      const int mt = m0 + t;
      const u16 hh = f2bf(ym);
      ymh[mt * 1536 + e] = hh;
      yml[mt * 1536 + e] = f2bf(ym - bf2f(hh));
    }
  }
}

// ---------------------------------------------------------------------------
// LayerNorm over 768 + affine -> bf16 hi/lo. One block per row.
// ---------------------------------------------------------------------------
__global__ __launch_bounds__(256) void k_ln(const float* __restrict__ g,
                                            const float* __restrict__ w,
                                            const float* __restrict__ bb,
                                            u16* __restrict__ xh,
                                            u16* __restrict__ xl) {
  const int m = blockIdx.x;
  const float* row = g + (size_t)m * 768;
  const int tid = threadIdx.x;
  const float v0 = row[tid], v1 = row[tid + 256], v2 = row[tid + 512];
  float s = v0 + v1 + v2;
#pragma unroll
  for (int o = 32; o > 0; o >>= 1) s += __shfl_xor(s, o);
  __shared__ float red[4];
  if ((tid & 63) == 0) red[tid >> 6] = s;
  __syncthreads();
  const float mu = (red[0] + red[1] + red[2] + red[3]) * (1.f / 768.f);
  const float d0 = v0 - mu, d1 = v1 - mu, d2 = v2 - mu;
  float q = d0 * d0 + d1 * d1 + d2 * d2;
#pragma unroll
  for (int o = 32; o > 0; o >>= 1) q += __shfl_xor(q, o);
  __syncthreads();
  if ((tid & 63) == 0) red[tid >> 6] = q;
  __syncthreads();
  const float var = (red[0] + red[1] + red[2] + red[3]) * (1.f / 768.f);
  const float rs = rsqrtf(var + 1e-5f);
  const float dd[3] = {d0, d1, d2};
#pragma unroll
  for (int i = 0; i < 3; ++i) {
    const int d = tid + i * 256;
    const float y = dd[i] * rs * w[d] + bb[d];
    const u16 h = f2bf(y);
    xh[(size_t)m * 768 + d] = h;
    xl[(size_t)m * 768 + d] = f2bf(y - bf2f(h));
  }
}

// ---------------------------------------------------------------------------
extern "C" void kernel_launch(void* const* d_in, const int* in_sizes, int n_in,
                              void* d_out, int out_size, void* d_ws, size_t ws_size,
                              hipStream_t stream) {
  const int* tokens = (const int*)d_in[0];
  const float* embed = (const float*)d_in[1];
  const float* in_w = (const float*)d_in[2];
  const float* conv_w = (const float*)d_in[3];
  const float* conv_b = (const float*)d_in[4];
  const float* xp_w = (const float*)d_in[5];
  const float* dt_w = (const float*)d_in[6];
  const float* dt_b = (const float*)d_in[7];
  const float* A_log = (const float*)d_in[8];
  const float* D_par = (const float*)d_in[9];
  const float* out_w = (const float*)d_in[10];
  const float* ln_w = (const float*)d_in[11];
  const float* ln_b = (const float*)d_in[12];
  const float* head_w = (const float*)d_in[13];
  const float* head_b = (const float*)d_in[14];

  char* p = (char*)d_ws;
  auto alloc = [&](size_t bytes) {
    char* r = p;
    p += (bytes + 255) & ~(size_t)255;
    return r;
  };
  float* xz = (float*)alloc(2048ull * 3072 * 4);     // in_proj out (xin | z)
  float* xinc = (float*)alloc(2048ull * 1536 * 4);   // conv+silu fp32
  u16* xih = (u16*)alloc(2048ull * 1536 * 2);        // conv+silu hi
  u16* xil = (u16*)alloc(2048ull * 1536 * 2);        // conv+silu lo
  float* dbc = (float*)alloc(2048ull * 80 * 4);      // x_proj out
  float* delta = (float*)alloc(2048ull * 1536 * 4);  // softplus(dt_proj)
  u16* ymh = (u16*)alloc(2048ull * 1536 * 2);        // gated scan out hi
  u16* yml = (u16*)alloc(2048ull * 1536 * 2);        // gated scan out lo
  float* gout = (float*)alloc(2048ull * 768 * 4);    // out_proj (pre-LN)
  u16* xh = (u16*)alloc(2048ull * 768 * 2);          // layer input hi
  u16* xl = (u16*)alloc(2048ull * 768 * 2);          // layer input lo
  u16* w_in_h = (u16*)alloc(2ull * 3072 * 768 * 2);  // bf16 weights
  u16* w_xp_h = (u16*)alloc(2ull * 80 * 1536 * 2);
  u16* w_out_h = (u16*)alloc(2ull * 768 * 1536 * 2);
  u16* w_head_h = (u16*)alloc(32000ull * 768 * 2);
  float* chP = (float*)alloc(2ull * SCAN_NC * 1536 * 16 * 4);  // chunk prod(dA)
  float* chQ = (float*)alloc(2ull * SCAN_NC * 1536 * 16 * 4);  // chunk local h
  float* hst = (float*)alloc(2ull * SCAN_NC * 1536 * 16 * 4);  // chunk h_start

  // weight bf16 pre-pass
  k_cvt<<<2048, 256, 0, stream>>>(in_w, w_in_h, 2 * 3072 * 768);
  k_cvt<<<256, 256, 0, stream>>>(xp_w, w_xp_h, 2 * 80 * 1536);
  k_cvt<<<1024, 256, 0, stream>>>(out_w, w_out_h, 2 * 768 * 1536);
  k_cvt<<<4096, 256, 0, stream>>>(head_w, w_head_h, 32000 * 768);

  k_embed<<<2048, 256, 0, stream>>>(tokens, embed, xh, xl);

  for (int l = 0; l < 2; ++l) {
    // in_proj: M=2048 N=3072 K=768 -> gemm2, grid 12*16=192 (192%8==0)
    gemm2<true, false><<<12 * 16, 512, 0, stream>>>(
        xh, xl, w_in_h + (size_t)l * 2359296, xz, nullptr, 2048, 3072, 768, 3072);

    k_conv<<<12288, 256, 0, stream>>>(xz, conv_w + l * 6144, conv_b + l * 1536, xinc, xih, xil);

    // x_proj: N=80 K=1536 -> split-K (KS=12, chunk 128) atomic into zeroed dbc
    k_zero<<<640, 256, 0, stream>>>(dbc, 2048 * 80);
    gemm_bt<true, false, true><<<dim3(1, 16, 12), 256, 0, stream>>>(
        xih, xil, w_xp_h + (size_t)l * 122880, dbc, nullptr, 2048, 80, 1536, 80, 128);

    k_dt<<<2048, 256, 0, stream>>>(dbc, dt_w + (size_t)l * 73728, dt_b + l * 1536, delta);

    k_scan1<<<dim3(96, 2, SCAN_NC), 256, 0, stream>>>(
        delta, xinc, dbc, A_log + l * 24576, chP, chQ);
    k_scan_fix<<<dim3(96, 2), 256, 0, stream>>>(chP, chQ, hst);
    k_scan2<<<dim3(96, 2, SCAN_NC), 256, 0, stream>>>(
        delta, xinc, dbc, xz, A_log + l * 24576, D_par + l * 1536, hst, ymh, yml);

    // out_proj: N=768 K=1536 -> split-K (KS=8, chunk 192) atomic into zeroed gout
    k_zero<<<6144, 256, 0, stream>>>(gout, 2048 * 768);
    gemm_bt<true, false, true><<<dim3(6, 16, 8), 256, 0, stream>>>(
        ymh, yml, w_out_h + (size_t)l * 1179648, gout, nullptr, 2048, 768, 1536, 768, 192);

    k_ln<<<2048, 256, 0, stream>>>(gout, ln_w + l * 768, ln_b + l * 768, xh, xl);
  }

  // head: M=2048 N=32000 K=768 -> gemm2, grid 125*16=2000 (2000%8==0)
  gemm2<true, true><<<125 * 16, 512, 0, stream>>>(
      xh, xl, w_head_h, (float*)d_out, head_b, 2048, 32000, 768, 32000);
}